// Round 16
// baseline (186.971 us; speedup 1.0000x reference)
//
#include <hip/hip_runtime.h>
#include <stdint.h>

#define WAVE 64
#define CIN 64
#define COUT 64
#define KS 5
#define KTOT 125   // 5^3
#define NSPLIT 16  // kNN candidate splits (3*NSPLIT must be <= 64)
#define BM 1e5f    // batch fold scale: BM*BM = 1e10 (reference mismatch penalty)

typedef __attribute__((ext_vector_type(8))) short short8v;  // 8 bf16 = 4 VGPRs
typedef __attribute__((ext_vector_type(4))) float f32x4;

__device__ inline unsigned long long wmin64(unsigned long long v) {
#pragma unroll
  for (int o = 32; o >= 1; o >>= 1) {
    unsigned long long u = __shfl_xor(v, o, 64);
    v = (u < v) ? u : v;
  }
  return v;
}

__device__ inline unsigned f32_orderable(float f) {
  unsigned fb = __float_as_uint(f);
  return (fb & 0x80000000u) ? ~fb : (fb | 0x80000000u);
}
__device__ inline float f32_unorderable(unsigned u) {
  unsigned fb = (u & 0x80000000u) ? (u & 0x7fffffffu) : ~u;
  return __uint_as_float(fb);
}

__device__ inline unsigned short f2bf(float f) {  // RNE
  unsigned u = __float_as_uint(f);
  unsigned r = (u + 0x7fffu + ((u >> 16) & 1u)) >> 16;
  return (unsigned short)r;
}
__device__ inline float bf2f(unsigned short v) {
  return __uint_as_float(((unsigned)v) << 16);
}

// ---- shared, contraction-proof d2 helpers (bit-identical everywhere) ----
__device__ __forceinline__ float qnorm4(float q0, float q1, float q2, float q3) {
  return fmaf(q0, q0, fmaf(q1, q1, fmaf(q2, q2, q3 * q3)));
}
__device__ __forceinline__ float dist2(float q0, float q1, float q2, float q3,
                                       float py2t, float4 c, float c3) {
  float dot = fmaf(q0, c.x, fmaf(q1, c.y, fmaf(q2, c.z, q3 * c3)));
  return fmaf(-2.f, dot, py2t + c.w);
}

__device__ inline void edge_basis(const float* __restrict__ pseudo, int e,
                                  float bas[8], int kidx[8]) {
  float v0 = pseudo[e * 3 + 0] * (float)(KS - 1);
  float v1 = pseudo[e * 3 + 1] * (float)(KS - 1);
  float v2 = pseudo[e * 3 + 2] * (float)(KS - 1);
  float l0 = floorf(v0), l1 = floorf(v1), l2 = floorf(v2);
  float f0 = v0 - l0, f1 = v1 - l1, f2 = v2 - l2;
  int i0 = (int)l0, i1 = (int)l1, i2 = (int)l2;
#pragma unroll
  for (int s = 0; s < 8; s++) {
    int b0 = s & 1, b1 = (s >> 1) & 1, b2 = (s >> 2) & 1;
    float bb = (b0 ? f0 : 1.f - f0) * (b1 ? f1 : 1.f - f1) * (b2 ? f2 : 1.f - f2);
    int j0 = i0 + b0; j0 = j0 < 0 ? 0 : (j0 > KS - 1 ? KS - 1 : j0);
    int j1 = i1 + b1; j1 = j1 < 0 ? 0 : (j1 > KS - 1 ? KS - 1 : j1);
    int j2 = i2 + b2; j2 = j2 < 0 ? 0 : (j2 > KS - 1 ? KS - 1 : j2);
    bas[s] = bb;
    kidx[s] = j0 + KS * j1 + KS * KS * j2;
  }
}

// ============ P: fused preamble — zero(acc,deg) | cvtx | cvtw | pack_posx ============
__global__ __launch_bounds__(256) void pre_kernel(
    const float* __restrict__ x, unsigned short* __restrict__ xbf, int n4,
    const float* __restrict__ Wf, unsigned short* __restrict__ wbf,
    const float* __restrict__ pos_x, const int* __restrict__ batch_x,
    float4* __restrict__ pxp4, float* __restrict__ pxb, int Nx_,
    float* __restrict__ zbase, int nz4, int nb_zero, int nb_cvtx) {
  __shared__ float L[64][68];
  int bid = blockIdx.x;
  int tid = threadIdx.x;

  if (bid < nb_zero) {  // ---- zero acc+deg ----
    int i = bid * 256 + tid;
    if (i < nz4) *(float4*)&zbase[i * 4] = make_float4(0.f, 0.f, 0.f, 0.f);
    return;
  }
  bid -= nb_zero;
  if (bid < nb_cvtx) {  // ---- cvtx ----
    int i = bid * 256 + tid;
    if (i >= n4) return;
    float4 v = *(const float4*)&x[i * 4];
    *(ushort4*)&xbf[i * 4] =
        make_ushort4(f2bf(v.x), f2bf(v.y), f2bf(v.z), f2bf(v.w));
    return;
  }
  bid -= nb_cvtx;
  if (bid < KTOT) {  // ---- cvtw ----
    int k = bid;
    {
      int i = tid >> 2, o0 = (tid & 3) * 16;
      const float* src = Wf + (size_t)k * 4096 + i * 64 + o0;
      float4 a = *(const float4*)src;
      float4 b = *(const float4*)(src + 4);
      float4 c = *(const float4*)(src + 8);
      float4 d = *(const float4*)(src + 12);
      *(float4*)&L[i][o0 + 0] = a;
      *(float4*)&L[i][o0 + 4] = b;
      *(float4*)&L[i][o0 + 8] = c;
      *(float4*)&L[i][o0 + 12] = d;
    }
    __syncthreads();
    int o = tid >> 2, i0 = (tid & 3) * 16;
    unsigned short* dst = wbf + (size_t)k * 4096 + o * 64 + i0;
#pragma unroll
    for (int g = 0; g < 4; g++) {
      *(ushort4*)&dst[g * 4] =
          make_ushort4(f2bf(L[i0 + g * 4 + 0][o]), f2bf(L[i0 + g * 4 + 1][o]),
                       f2bf(L[i0 + g * 4 + 2][o]), f2bf(L[i0 + g * 4 + 3][o]));
    }
    return;
  }
  bid -= KTOT;
  {  // ---- pack_posx ----
    int t = bid * 256 + tid;
    if (t >= Nx_) return;
    float a0 = pos_x[t * 3 + 0], a1 = pos_x[t * 3 + 1], a2 = pos_x[t * 3 + 2];
    float bm = (float)batch_x[t] * BM;
    pxp4[t] = make_float4(a0, a1, a2, qnorm4(a0, a1, a2, bm));
    pxb[t] = bm;
  }
}

// ============ Q: INTERLEAVED — knn_val every S-th block | xw_mfma ============
__global__ __launch_bounds__(256) void phaseQ_kernel(
    // knn_val args
    const float4* __restrict__ pxp4, const float* __restrict__ pxb,
    const float* __restrict__ pos_y, const int* __restrict__ batch_y,
    const int* __restrict__ kptr, float* __restrict__ vpart,
    int Ny_, int csize, int nb_knn, int nqb, int S,
    // xw args
    const unsigned short* __restrict__ xbf,
    const unsigned short* __restrict__ wbf,
    unsigned short* __restrict__ xw, int Nx_, int nxb) {
  __shared__ char smem[8192];
  int bid = blockIdx.x;
  int tid = threadIdx.x;

  int strip = bid / S;
  bool isKnn = (bid % S == 0) && (strip < nb_knn);

  if (isKnn) {  // ---- knn_val (verbatim math) ----
    if (*kptr > 3) return;
    float4* lc = (float4*)smem;
    float* lb = (float*)(smem + 4096);
    const float FINF = __uint_as_float(0x7f800000u);

    int split = strip / nqb;
    int qy = (strip % nqb) * 256 + tid;
    int base0 = split * csize;

    int qc = qy < Ny_ ? qy : Ny_ - 1;
    float q0 = pos_y[qc * 3 + 0], q1 = pos_y[qc * 3 + 1], q2 = pos_y[qc * 3 + 2];
    float q3 = (float)batch_y[qc] * BM;
    float py2t = qnorm4(q0, q1, q2, q3);

    float b0 = FINF, b1 = FINF, b2 = FINF;

    for (int tb = 0; tb < csize; tb += 256) {
      int t = base0 + tb + tid;
      float4 cv;
      float cb;
      if (t < Nx_) {
        cv = pxp4[t];
        cb = pxb[t];
      } else {
        cv = make_float4(0.f, 0.f, 0.f, FINF);
        cb = 0.f;
      }
      __syncthreads();
      lc[tid] = cv;
      lb[tid] = cb;
      __syncthreads();

#pragma unroll 4
      for (int j = 0; j < 256; j++) {
        float d2 = dist2(q0, q1, q2, q3, py2t, lc[j], lb[j]);
        float n0 = fminf(d2, b0);
        float n1 = fminf(fmaxf(d2, b0), b1);
        float n2 = fminf(fmaxf(d2, b1), b2);
        b0 = n0; b1 = n1; b2 = n2;
      }
    }

    if (qy < Ny_) {
      float* vp = vpart + ((size_t)split * Ny_ + qy) * 3;
      vp[0] = b0;
      vp[1] = b1;
      vp[2] = b2;
    }
    return;
  }

  // ---- xw_mfma (verbatim) ----
  {
    int nknn_below = (bid + S - 1) / S;
    if (nknn_below > nb_knn) nknn_below = nb_knn;
    int b = bid - nknn_below;
    int n0 = (b % nxb) * 64;
    int k = b / nxb;
    unsigned short(*Sm)[64] = (unsigned short(*)[64])smem;

    int w = tid >> 6, lane = tid & 63;
    int lr = lane & 15, kg = lane >> 4;
    int rA = n0 + w * 16 + lr;
    if (rA >= Nx_) rA = Nx_ - 1;

    short8v a0 = *(const short8v*)&xbf[(size_t)rA * CIN + kg * 8];
    short8v a1 = *(const short8v*)&xbf[(size_t)rA * CIN + 32 + kg * 8];

    const unsigned short* wb = wbf + (size_t)k * 4096;
#pragma unroll
    for (int ct = 0; ct < 4; ct++) {
      int col = ct * 16 + lr;
      short8v b0 = *(const short8v*)&wb[col * 64 + kg * 8];
      short8v b1 = *(const short8v*)&wb[col * 64 + 32 + kg * 8];
      f32x4 c = {0.f, 0.f, 0.f, 0.f};
      c = __builtin_amdgcn_mfma_f32_16x16x32_bf16(a0, b0, c, 0, 0, 0);
      c = __builtin_amdgcn_mfma_f32_16x16x32_bf16(a1, b1, c, 0, 0, 0);
#pragma unroll
      for (int r = 0; r < 4; r++) {
        Sm[w * 16 + kg * 4 + r][ct * 16 + lr] = f2bf(c[r]);
      }
    }
    __syncthreads();

#pragma unroll
    for (int round = 0; round < 2; round++) {
      int rr = (tid >> 3) + round * 32;
      int ch = (tid & 7) * 8;
      int grow = n0 + rr;
      if (grow < Nx_) {
        uint4 v = *(const uint4*)&Sm[rr][ch];
        *(uint4*)&xw[((size_t)k * Nx_ + grow) * COUT + ch] = v;
      }
    }
  }
}

// ============ R: INTERLEAVED — knn_rec every S-th block | edge_sum ============
__global__ __launch_bounds__(256) void phaseR_kernel(
    // knn_rec args
    const float* __restrict__ vpart,
    const float4* __restrict__ pxp4, const float* __restrict__ pxb,
    const float* __restrict__ pos_y, const int* __restrict__ batch_y,
    const int* __restrict__ kptr, unsigned long long* __restrict__ part,
    int Ny_, int csize, int nb_knn, int nqb, int S,
    // edge_sum args
    const int* __restrict__ ei, const float* __restrict__ pseudo,
    const unsigned short* __restrict__ xw, float* __restrict__ acc,
    float* __restrict__ deg, int E_, int Nx_) {
  __shared__ char smem[5120];
  int bid = blockIdx.x;
  int tid = threadIdx.x;

  int strip = bid / S;
  bool isKnn = (bid % S == 0) && (strip < nb_knn);

  if (isKnn) {  // ---- knn_rec (verbatim math) ----
    int kk = *kptr;
    if (kk > 3) return;
    kk = kk < 1 ? 1 : kk;
    float4* lc = (float4*)smem;
    float* lb = (float*)(smem + 4096);
    const float FINF = __uint_as_float(0x7f800000u);

    int split = strip / nqb;
    int qy = (strip % nqb) * 256 + tid;
    int base0 = split * csize;

    int qc = qy < Ny_ ? qy : Ny_ - 1;
    float q0 = pos_y[qc * 3 + 0], q1 = pos_y[qc * 3 + 1], q2 = pos_y[qc * 3 + 2];
    float q3 = (float)batch_y[qc] * BM;
    float py2t = qnorm4(q0, q1, q2, q3);

    float t0v = FINF, t1v = FINF, t2v = FINF;
#pragma unroll
    for (int s = 0; s < NSPLIT; s++) {
      const float* vp = vpart + ((size_t)s * Ny_ + qc) * 3;
#pragma unroll
      for (int r = 0; r < 3; r++) {
        float v = vp[r];
        float n0 = fminf(v, t0v);
        float n1 = fminf(fmaxf(v, t0v), t1v);
        float n2 = fminf(fmaxf(v, t1v), t2v);
        t0v = n0; t1v = n1; t2v = n2;
      }
    }
    float thr = kk == 1 ? t0v : (kk == 2 ? t1v : t2v);

    unsigned long long k0 = ~0ull, k1 = ~0ull, k2 = ~0ull;

    for (int tb = 0; tb < csize; tb += 256) {
      int t = base0 + tb + tid;
      float4 cv;
      float cb;
      if (t < Nx_) {
        cv = pxp4[t];
        cb = pxb[t];
      } else {
        cv = make_float4(0.f, 0.f, 0.f, FINF);
        cb = 0.f;
      }
      __syncthreads();
      lc[tid] = cv;
      lb[tid] = cb;
      __syncthreads();

#pragma unroll 4
      for (int j = 0; j < 256; j++) {
        float d2 = dist2(q0, q1, q2, q3, py2t, lc[j], lb[j]);
        if (d2 <= thr) {
          unsigned long long key =
              (((unsigned long long)f32_orderable(d2)) << 32) |
              (unsigned)(base0 + tb + j);
          {
            bool lt = key < k0;
            unsigned long long nv = lt ? key : k0;
            unsigned long long xv = lt ? k0 : key;
            k0 = nv; key = xv;
          }
          {
            bool lt = key < k1;
            unsigned long long nv = lt ? key : k1;
            unsigned long long xv = lt ? k1 : key;
            k1 = nv; key = xv;
          }
          k2 = key < k2 ? key : k2;
        }
      }
    }

    if (qy < Ny_) {
      unsigned long long* pp = part + ((size_t)split * Ny_ + qy) * 3;
      pp[0] = k0;
      pp[1] = k1;
      pp[2] = k2;
    }
    return;
  }

  // ---- edge_sum (verbatim) ----
  {
    int nknn_below = (bid + S - 1) / S;
    if (nknn_below > nb_knn) nknn_below = nb_knn;
    int b = bid - nknn_below;
    int lane = tid & 63;
    int e = (int)(((size_t)b * 256 + tid) >> 6);
    if (e >= E_) return;
    int src = ei[e];
    int dst = ei[E_ + e];
    float bas[8];
    int kidx[8];
    edge_basis(pseudo, e, bas, kidx);

    float y = 0.f;
#pragma unroll
    for (int s = 0; s < 8; s++) {
      y = fmaf(bas[s], bf2f(xw[((size_t)kidx[s] * Nx_ + src) * COUT + lane]), y);
    }
    atomicAdd(&acc[(size_t)dst * COUT + lane], y);
    if (lane == 0) atomicAdd(&deg[dst], 1.f);
  }
}

// ---------- node finish ----------
__global__ void node_finish_kernel(const float* __restrict__ x,
                                   const float* __restrict__ root,
                                   const float* __restrict__ bias,
                                   const float* __restrict__ acc,
                                   const float* __restrict__ deg,
                                   float* __restrict__ h, int Nx_) {
  int lane = threadIdx.x & 63;
  int n = (int)((blockIdx.x * blockDim.x + threadIdx.x) >> 6);
  if (n >= Nx_) return;
  float xs = x[(size_t)n * CIN + lane];
  float r = 0.f;
#pragma unroll 4
  for (int i = 0; i < CIN; i++) {
    float xv = __shfl(xs, i, 64);
    r = fmaf(xv, root[i * COUT + lane], r);
  }
  float d = deg[n];
  d = d > 1.f ? d : 1.f;
  float o = acc[(size_t)n * COUT + lane] / d + r + bias[lane];
  h[(size_t)n * COUT + lane] = (o > 0.f) ? o : expm1f(o);
}

// ---------- kNN merge + interp ----------
__global__ void knn_merge_kernel(const unsigned long long* __restrict__ part,
                                 const float* __restrict__ h,
                                 const int* __restrict__ kptr,
                                 float* __restrict__ out, int Nx_, int Ny_) {
  int kk = *kptr;
  if (kk > 3) return;  // generic path handles
  kk = kk < 1 ? 1 : kk;
  int lane = threadIdx.x & 63;
  int qy = (int)((blockIdx.x * blockDim.x + threadIdx.x) >> 6);
  if (qy >= Ny_) return;

  unsigned long long key = ~0ull;
  if (lane < 3 * NSPLIT) {
    key = part[((size_t)(lane / 3) * Ny_ + qy) * 3 + (lane % 3)];
  }

  float num = 0.f, den = 0.f;
  for (int i = 0; i < kk; i++) {
    unsigned long long m = wmin64(key);
    if (key == m) key = ~0ull;
    unsigned u = (unsigned)(m >> 32);
    int idx = (int)(m & 0xffffffffu);
    idx = (idx < 0 || idx >= Nx_) ? 0 : idx;
    float d2 = f32_unorderable(u);
    float w = 1.f / fmaxf(d2, 1e-16f);
    num = fmaf(w, h[(size_t)idx * COUT + lane], num);
    den += w;
  }
  out[(size_t)qy * COUT + lane] = num / den;
}

// ---------- generic k>3 fallback ----------
__global__ void knn_generic_kernel(const float* __restrict__ h,
                                   const float4* __restrict__ pxp4,
                                   const float* __restrict__ pxb,
                                   const float* __restrict__ pos_y,
                                   const int* __restrict__ batch_y,
                                   const int* __restrict__ kptr,
                                   float* __restrict__ out,
                                   int Nx_, int Ny_) {
  int kk = *kptr;
  if (kk <= 3) return;  // fast path handles
  kk = kk > 8 ? 8 : kk;
  int lane = threadIdx.x & 63;
  int yy = (int)((blockIdx.x * blockDim.x + threadIdx.x) >> 6);
  if (yy >= Ny_) return;

  float q0 = pos_y[yy * 3 + 0], q1 = pos_y[yy * 3 + 1], q2 = pos_y[yy * 3 + 2];
  float q3 = (float)batch_y[yy] * BM;
  float py2t = qnorm4(q0, q1, q2, q3);

  unsigned long long best[8];
#pragma unroll
  for (int j = 0; j < 8; j++) best[j] = ~0ull;

  for (int t0 = 0; t0 < Nx_; t0 += 64) {
    int t = t0 + lane;
    unsigned long long key = ~0ull;
    if (t < Nx_) {
      float d2 = dist2(q0, q1, q2, q3, py2t, pxp4[t], pxb[t]);
      key = (((unsigned long long)f32_orderable(d2)) << 32) | (unsigned)t;
    }
    if (key < best[7]) {
#pragma unroll
      for (int j = 0; j < 8; j++) {
        unsigned long long mn = key < best[j] ? key : best[j];
        unsigned long long mx = key < best[j] ? best[j] : key;
        best[j] = mn;
        key = mx;
      }
    }
  }

  float num = 0.f, den = 0.f;
  for (int j = 0; j < kk; j++) {
    unsigned long long m = wmin64(best[0]);
    if (best[0] == m) {
#pragma unroll
      for (int t = 0; t < 7; t++) best[t] = best[t + 1];
      best[7] = ~0ull;
    }
    unsigned u = (unsigned)(m >> 32);
    int idx = (int)(m & 0xffffffffu);
    idx = (idx < 0 || idx >= Nx_) ? 0 : idx;
    float d2 = f32_unorderable(u);
    float w = 1.f / fmaxf(d2, 1e-16f);
    num = fmaf(w, h[(size_t)idx * COUT + lane], num);
    den += w;
  }
  out[(size_t)yy * COUT + lane] = num / den;
}

extern "C" void kernel_launch(void* const* d_in, const int* in_sizes, int n_in,
                              void* d_out, int out_size, void* d_ws, size_t ws_size,
                              hipStream_t stream) {
  const float* x = (const float*)d_in[0];
  const float* pos_x = (const float*)d_in[1];
  const float* pos_y = (const float*)d_in[2];
  const int* eidx = (const int*)d_in[3];
  const float* pseudo = (const float*)d_in[4];
  const int* batch_x = (const int*)d_in[5];
  const int* batch_y = (const int*)d_in[6];
  const float* W = (const float*)d_in[7];   // [125,64,64]
  const float* root = (const float*)d_in[8];
  const float* bias = (const float*)d_in[9];
  const int* kptr = (const int*)d_in[10];

  int Nx = in_sizes[0] / CIN;
  int Ny = in_sizes[2] / 3;
  int E = in_sizes[3] / 2;

  int csize = ((Nx + NSPLIT - 1) / NSPLIT + 255) & ~255;
  if (csize < 256) csize = 256;

  // ws layout: acc[Nx*64]f | deg[Nx]f | h[Nx*64]f | pxp4[Nx]float4 | pxb[Nx]f |
  //   xbf[Nx*64]u16 | wbf[125*4096]u16 | xw[125*Nx*64]u16 |
  //   vpart[NSPLIT*Ny*3]f | part[NSPLIT*Ny*3]u64
  float* acc = (float*)d_ws;
  float* deg = acc + (size_t)Nx * COUT;
  float* h = deg + Nx;
  float4* pxp4 = (float4*)(h + (size_t)Nx * COUT);
  float* pxb = (float*)(pxp4 + Nx);
  unsigned short* xbf = (unsigned short*)(pxb + Nx);
  unsigned short* wbf = xbf + (size_t)Nx * CIN;
  unsigned short* xw = wbf + (size_t)KTOT * CIN * COUT;
  float* vpart = (float*)(xw + (size_t)Nx * KTOT * COUT);
  uintptr_t paddr = (uintptr_t)(vpart + (size_t)NSPLIT * Ny * 3);
  paddr = (paddr + 7) & ~(uintptr_t)7;
  unsigned long long* part = (unsigned long long*)paddr;

  float* out = (float*)d_out;

  int n4 = Nx * CIN / 4;
  int nb_cvtx = (n4 + 255) / 256;
  int nb_pack = (Nx + 255) / 256;
  int nz4 = (Nx * COUT + Nx) / 4;          // acc+deg floats / 4 (Nx*65 % 4 == 0)
  int nb_zero = (nz4 + 255) / 256;
  int nqb = (Ny + 255) / 256;
  int nb_knn = nqb * NSPLIT;
  int nxb = (Nx + 63) / 64;
  int nb_xw = nxb * KTOT;
  int nb_edge = (int)(((size_t)E * WAVE + 255) / 256);

  // P: zero | cvtx | cvtw | pack
  pre_kernel<<<nb_zero + nb_cvtx + KTOT + nb_pack, 256, 0, stream>>>(
      x, xbf, n4, W, wbf, pos_x, batch_x, pxp4, pxb, Nx, acc, nz4, nb_zero,
      nb_cvtx);

  // Q: interleaved knn_val | xw_mfma
  {
    int total = nb_knn + nb_xw;
    int S = total / nb_knn;
    if (S < 1) S = 1;
    phaseQ_kernel<<<total, 256, 0, stream>>>(
        pxp4, pxb, pos_y, batch_y, kptr, vpart, Ny, csize, nb_knn, nqb, S,
        xbf, wbf, xw, Nx, nxb);
  }

  // R: interleaved knn_rec | edge_sum
  {
    int total = nb_knn + nb_edge;
    int S = total / nb_knn;
    if (S < 1) S = 1;
    phaseR_kernel<<<total, 256, 0, stream>>>(
        vpart, pxp4, pxb, pos_y, batch_y, kptr, part, Ny, csize, nb_knn, nqb, S,
        eidx, pseudo, xw, acc, deg, E, Nx);
  }

  {
    int blocks = (Nx * WAVE + 255) / 256;
    node_finish_kernel<<<blocks, 256, 0, stream>>>(x, root, bias, acc, deg, h, Nx);
  }
  {
    int blocks = (Ny * WAVE + 255) / 256;
    knn_merge_kernel<<<blocks, 256, 0, stream>>>(part, h, kptr, out, Nx, Ny);
    knn_generic_kernel<<<blocks, 256, 0, stream>>>(h, pxp4, pxb, pos_y, batch_y,
                                                   kptr, out, Nx, Ny);
  }
}

// Round 17
// 147.189 us; speedup vs baseline: 1.2703x; 1.2703x over previous
//
#include <hip/hip_runtime.h>
#include <stdint.h>

#define WAVE 64
#define CIN 64
#define COUT 64
#define KS 5
#define KTOT 125   // 5^3
#define NSPLIT 16  // kNN candidate splits (3*NSPLIT must be <= 64)
#define BM 1e5f    // batch fold scale: BM*BM = 1e10 (reference mismatch penalty)

typedef __attribute__((ext_vector_type(8))) short short8v;  // 8 bf16 = 4 VGPRs
typedef __attribute__((ext_vector_type(4))) float f32x4;

__device__ inline unsigned long long wmin64(unsigned long long v) {
#pragma unroll
  for (int o = 32; o >= 1; o >>= 1) {
    unsigned long long u = __shfl_xor(v, o, 64);
    v = (u < v) ? u : v;
  }
  return v;
}

__device__ inline unsigned f32_orderable(float f) {
  unsigned fb = __float_as_uint(f);
  return (fb & 0x80000000u) ? ~fb : (fb | 0x80000000u);
}
__device__ inline float f32_unorderable(unsigned u) {
  unsigned fb = (u & 0x80000000u) ? (u & 0x7fffffffu) : ~u;
  return __uint_as_float(fb);
}

__device__ inline unsigned short f2bf(float f) {  // RNE
  unsigned u = __float_as_uint(f);
  unsigned r = (u + 0x7fffu + ((u >> 16) & 1u)) >> 16;
  return (unsigned short)r;
}
__device__ inline float bf2f(unsigned short v) {
  return __uint_as_float(((unsigned)v) << 16);
}

// ---- shared, contraction-proof d2 helpers (bit-identical everywhere) ----
__device__ __forceinline__ float qnorm4(float q0, float q1, float q2, float q3) {
  return fmaf(q0, q0, fmaf(q1, q1, fmaf(q2, q2, q3 * q3)));
}
__device__ __forceinline__ float dist2(float q0, float q1, float q2, float q3,
                                       float py2t, float4 c, float c3) {
  float dot = fmaf(q0, c.x, fmaf(q1, c.y, fmaf(q2, c.z, q3 * c3)));
  return fmaf(-2.f, dot, py2t + c.w);
}

__device__ inline void edge_basis(const float* __restrict__ pseudo, int e,
                                  float bas[8], int kidx[8]) {
  float v0 = pseudo[e * 3 + 0] * (float)(KS - 1);
  float v1 = pseudo[e * 3 + 1] * (float)(KS - 1);
  float v2 = pseudo[e * 3 + 2] * (float)(KS - 1);
  float l0 = floorf(v0), l1 = floorf(v1), l2 = floorf(v2);
  float f0 = v0 - l0, f1 = v1 - l1, f2 = v2 - l2;
  int i0 = (int)l0, i1 = (int)l1, i2 = (int)l2;
#pragma unroll
  for (int s = 0; s < 8; s++) {
    int b0 = s & 1, b1 = (s >> 1) & 1, b2 = (s >> 2) & 1;
    float bb = (b0 ? f0 : 1.f - f0) * (b1 ? f1 : 1.f - f1) * (b2 ? f2 : 1.f - f2);
    int j0 = i0 + b0; j0 = j0 < 0 ? 0 : (j0 > KS - 1 ? KS - 1 : j0);
    int j1 = i1 + b1; j1 = j1 < 0 ? 0 : (j1 > KS - 1 ? KS - 1 : j1);
    int j2 = i2 + b2; j2 = j2 < 0 ? 0 : (j2 > KS - 1 ? KS - 1 : j2);
    bas[s] = bb;
    kidx[s] = j0 + KS * j1 + KS * KS * j2;
  }
}

// ---- XCD-safe interleave: knn block of strip s sits at position s%S in strip ----
// consecutive knn bids step S+1 -> cycle through all XCD residues.
__device__ __forceinline__ bool route_knn(int bid, int S, int nb_knn,
                                          int* knn_id, int* other_id) {
  int strip = bid / S;
  int pos = bid - strip * S;
  int slot = strip % S;
  bool isKnn = (strip < nb_knn) && (pos == slot);
  *knn_id = strip;
  int below = (strip < nb_knn) ? (strip + (pos > slot ? 1 : 0)) : nb_knn;
  *other_id = bid - below;
  return isKnn;
}

// ============ P: fused preamble — zero(acc,deg) | cvtx | cvtw | pack_posx ============
__global__ __launch_bounds__(256) void pre_kernel(
    const float* __restrict__ x, unsigned short* __restrict__ xbf, int n4,
    const float* __restrict__ Wf, unsigned short* __restrict__ wbf,
    const float* __restrict__ pos_x, const int* __restrict__ batch_x,
    float4* __restrict__ pxp4, float* __restrict__ pxb, int Nx_,
    float* __restrict__ zbase, int nz4, int nb_zero, int nb_cvtx) {
  __shared__ float L[64][68];
  int bid = blockIdx.x;
  int tid = threadIdx.x;

  if (bid < nb_zero) {  // ---- zero acc+deg ----
    int i = bid * 256 + tid;
    if (i < nz4) *(float4*)&zbase[i * 4] = make_float4(0.f, 0.f, 0.f, 0.f);
    return;
  }
  bid -= nb_zero;
  if (bid < nb_cvtx) {  // ---- cvtx ----
    int i = bid * 256 + tid;
    if (i >= n4) return;
    float4 v = *(const float4*)&x[i * 4];
    *(ushort4*)&xbf[i * 4] =
        make_ushort4(f2bf(v.x), f2bf(v.y), f2bf(v.z), f2bf(v.w));
    return;
  }
  bid -= nb_cvtx;
  if (bid < KTOT) {  // ---- cvtw ----
    int k = bid;
    {
      int i = tid >> 2, o0 = (tid & 3) * 16;
      const float* src = Wf + (size_t)k * 4096 + i * 64 + o0;
      float4 a = *(const float4*)src;
      float4 b = *(const float4*)(src + 4);
      float4 c = *(const float4*)(src + 8);
      float4 d = *(const float4*)(src + 12);
      *(float4*)&L[i][o0 + 0] = a;
      *(float4*)&L[i][o0 + 4] = b;
      *(float4*)&L[i][o0 + 8] = c;
      *(float4*)&L[i][o0 + 12] = d;
    }
    __syncthreads();
    int o = tid >> 2, i0 = (tid & 3) * 16;
    unsigned short* dst = wbf + (size_t)k * 4096 + o * 64 + i0;
#pragma unroll
    for (int g = 0; g < 4; g++) {
      *(ushort4*)&dst[g * 4] =
          make_ushort4(f2bf(L[i0 + g * 4 + 0][o]), f2bf(L[i0 + g * 4 + 1][o]),
                       f2bf(L[i0 + g * 4 + 2][o]), f2bf(L[i0 + g * 4 + 3][o]));
    }
    return;
  }
  bid -= KTOT;
  {  // ---- pack_posx ----
    int t = bid * 256 + tid;
    if (t >= Nx_) return;
    float a0 = pos_x[t * 3 + 0], a1 = pos_x[t * 3 + 1], a2 = pos_x[t * 3 + 2];
    float bm = (float)batch_x[t] * BM;
    pxp4[t] = make_float4(a0, a1, a2, qnorm4(a0, a1, a2, bm));
    pxb[t] = bm;
  }
}

// ============ Q: XCD-safe interleaved — knn_val | xw_mfma ============
__global__ __launch_bounds__(256) void phaseQ_kernel(
    const float4* __restrict__ pxp4, const float* __restrict__ pxb,
    const float* __restrict__ pos_y, const int* __restrict__ batch_y,
    const int* __restrict__ kptr, float* __restrict__ vpart,
    int Ny_, int csize, int nb_knn, int nqb, int S,
    const unsigned short* __restrict__ xbf,
    const unsigned short* __restrict__ wbf,
    unsigned short* __restrict__ xw, int Nx_, int nxb) {
  __shared__ char smem[8192];
  int bid = blockIdx.x;
  int tid = threadIdx.x;

  int knn_id, other_id;
  bool isKnn = route_knn(bid, S, nb_knn, &knn_id, &other_id);

  if (isKnn) {  // ---- knn_val (verbatim math) ----
    if (*kptr > 3) return;
    float4* lc = (float4*)smem;
    float* lb = (float*)(smem + 4096);
    const float FINF = __uint_as_float(0x7f800000u);

    int split = knn_id / nqb;
    int qy = (knn_id % nqb) * 256 + tid;
    int base0 = split * csize;

    int qc = qy < Ny_ ? qy : Ny_ - 1;
    float q0 = pos_y[qc * 3 + 0], q1 = pos_y[qc * 3 + 1], q2 = pos_y[qc * 3 + 2];
    float q3 = (float)batch_y[qc] * BM;
    float py2t = qnorm4(q0, q1, q2, q3);

    float b0 = FINF, b1 = FINF, b2 = FINF;

    for (int tb = 0; tb < csize; tb += 256) {
      int t = base0 + tb + tid;
      float4 cv;
      float cb;
      if (t < Nx_) {
        cv = pxp4[t];
        cb = pxb[t];
      } else {
        cv = make_float4(0.f, 0.f, 0.f, FINF);
        cb = 0.f;
      }
      __syncthreads();
      lc[tid] = cv;
      lb[tid] = cb;
      __syncthreads();

#pragma unroll 4
      for (int j = 0; j < 256; j++) {
        float d2 = dist2(q0, q1, q2, q3, py2t, lc[j], lb[j]);
        float n0 = fminf(d2, b0);
        float n1 = fminf(fmaxf(d2, b0), b1);
        float n2 = fminf(fmaxf(d2, b1), b2);
        b0 = n0; b1 = n1; b2 = n2;
      }
    }

    if (qy < Ny_) {
      float* vp = vpart + ((size_t)split * Ny_ + qy) * 3;
      vp[0] = b0;
      vp[1] = b1;
      vp[2] = b2;
    }
    return;
  }

  // ---- xw_mfma (verbatim) ----
  {
    int b = other_id;
    int n0 = (b % nxb) * 64;
    int k = b / nxb;
    unsigned short(*Sm)[64] = (unsigned short(*)[64])smem;

    int w = tid >> 6, lane = tid & 63;
    int lr = lane & 15, kg = lane >> 4;
    int rA = n0 + w * 16 + lr;
    if (rA >= Nx_) rA = Nx_ - 1;

    short8v a0 = *(const short8v*)&xbf[(size_t)rA * CIN + kg * 8];
    short8v a1 = *(const short8v*)&xbf[(size_t)rA * CIN + 32 + kg * 8];

    const unsigned short* wb = wbf + (size_t)k * 4096;
#pragma unroll
    for (int ct = 0; ct < 4; ct++) {
      int col = ct * 16 + lr;
      short8v b0 = *(const short8v*)&wb[col * 64 + kg * 8];
      short8v b1 = *(const short8v*)&wb[col * 64 + 32 + kg * 8];
      f32x4 c = {0.f, 0.f, 0.f, 0.f};
      c = __builtin_amdgcn_mfma_f32_16x16x32_bf16(a0, b0, c, 0, 0, 0);
      c = __builtin_amdgcn_mfma_f32_16x16x32_bf16(a1, b1, c, 0, 0, 0);
#pragma unroll
      for (int r = 0; r < 4; r++) {
        Sm[w * 16 + kg * 4 + r][ct * 16 + lr] = f2bf(c[r]);
      }
    }
    __syncthreads();

#pragma unroll
    for (int round = 0; round < 2; round++) {
      int rr = (tid >> 3) + round * 32;
      int ch = (tid & 7) * 8;
      int grow = n0 + rr;
      if (grow < Nx_) {
        uint4 v = *(const uint4*)&Sm[rr][ch];
        *(uint4*)&xw[((size_t)k * Nx_ + grow) * COUT + ch] = v;
      }
    }
  }
}

// ============ R: XCD-safe interleaved — knn_rec | edge_sum ============
__global__ __launch_bounds__(256) void phaseR_kernel(
    const float* __restrict__ vpart,
    const float4* __restrict__ pxp4, const float* __restrict__ pxb,
    const float* __restrict__ pos_y, const int* __restrict__ batch_y,
    const int* __restrict__ kptr, unsigned long long* __restrict__ part,
    int Ny_, int csize, int nb_knn, int nqb, int S,
    const int* __restrict__ ei, const float* __restrict__ pseudo,
    const unsigned short* __restrict__ xw, float* __restrict__ acc,
    float* __restrict__ deg, int E_, int Nx_) {
  __shared__ char smem[5120];
  int bid = blockIdx.x;
  int tid = threadIdx.x;

  int knn_id, other_id;
  bool isKnn = route_knn(bid, S, nb_knn, &knn_id, &other_id);

  if (isKnn) {  // ---- knn_rec (verbatim math) ----
    int kk = *kptr;
    if (kk > 3) return;
    kk = kk < 1 ? 1 : kk;
    float4* lc = (float4*)smem;
    float* lb = (float*)(smem + 4096);
    const float FINF = __uint_as_float(0x7f800000u);

    int split = knn_id / nqb;
    int qy = (knn_id % nqb) * 256 + tid;
    int base0 = split * csize;

    int qc = qy < Ny_ ? qy : Ny_ - 1;
    float q0 = pos_y[qc * 3 + 0], q1 = pos_y[qc * 3 + 1], q2 = pos_y[qc * 3 + 2];
    float q3 = (float)batch_y[qc] * BM;
    float py2t = qnorm4(q0, q1, q2, q3);

    float t0v = FINF, t1v = FINF, t2v = FINF;
#pragma unroll
    for (int s = 0; s < NSPLIT; s++) {
      const float* vp = vpart + ((size_t)s * Ny_ + qc) * 3;
#pragma unroll
      for (int r = 0; r < 3; r++) {
        float v = vp[r];
        float n0 = fminf(v, t0v);
        float n1 = fminf(fmaxf(v, t0v), t1v);
        float n2 = fminf(fmaxf(v, t1v), t2v);
        t0v = n0; t1v = n1; t2v = n2;
      }
    }
    float thr = kk == 1 ? t0v : (kk == 2 ? t1v : t2v);

    unsigned long long k0 = ~0ull, k1 = ~0ull, k2 = ~0ull;

    for (int tb = 0; tb < csize; tb += 256) {
      int t = base0 + tb + tid;
      float4 cv;
      float cb;
      if (t < Nx_) {
        cv = pxp4[t];
        cb = pxb[t];
      } else {
        cv = make_float4(0.f, 0.f, 0.f, FINF);
        cb = 0.f;
      }
      __syncthreads();
      lc[tid] = cv;
      lb[tid] = cb;
      __syncthreads();

#pragma unroll 4
      for (int j = 0; j < 256; j++) {
        float d2 = dist2(q0, q1, q2, q3, py2t, lc[j], lb[j]);
        if (d2 <= thr) {
          unsigned long long key =
              (((unsigned long long)f32_orderable(d2)) << 32) |
              (unsigned)(base0 + tb + j);
          {
            bool lt = key < k0;
            unsigned long long nv = lt ? key : k0;
            unsigned long long xv = lt ? k0 : key;
            k0 = nv; key = xv;
          }
          {
            bool lt = key < k1;
            unsigned long long nv = lt ? key : k1;
            unsigned long long xv = lt ? k1 : key;
            k1 = nv; key = xv;
          }
          k2 = key < k2 ? key : k2;
        }
      }
    }

    if (qy < Ny_) {
      unsigned long long* pp = part + ((size_t)split * Ny_ + qy) * 3;
      pp[0] = k0;
      pp[1] = k1;
      pp[2] = k2;
    }
    return;
  }

  // ---- edge_sum (verbatim) ----
  {
    int b = other_id;
    int lane = tid & 63;
    int e = (int)(((size_t)b * 256 + tid) >> 6);
    if (e >= E_) return;
    int src = ei[e];
    int dst = ei[E_ + e];
    float bas[8];
    int kidx[8];
    edge_basis(pseudo, e, bas, kidx);

    float y = 0.f;
#pragma unroll
    for (int s = 0; s < 8; s++) {
      y = fmaf(bas[s], bf2f(xw[((size_t)kidx[s] * Nx_ + src) * COUT + lane]), y);
    }
    atomicAdd(&acc[(size_t)dst * COUT + lane], y);
    if (lane == 0) atomicAdd(&deg[dst], 1.f);
  }
}

// ---------- node finish ----------
__global__ void node_finish_kernel(const float* __restrict__ x,
                                   const float* __restrict__ root,
                                   const float* __restrict__ bias,
                                   const float* __restrict__ acc,
                                   const float* __restrict__ deg,
                                   float* __restrict__ h, int Nx_) {
  int lane = threadIdx.x & 63;
  int n = (int)((blockIdx.x * blockDim.x + threadIdx.x) >> 6);
  if (n >= Nx_) return;
  float xs = x[(size_t)n * CIN + lane];
  float r = 0.f;
#pragma unroll 4
  for (int i = 0; i < CIN; i++) {
    float xv = __shfl(xs, i, 64);
    r = fmaf(xv, root[i * COUT + lane], r);
  }
  float d = deg[n];
  d = d > 1.f ? d : 1.f;
  float o = acc[(size_t)n * COUT + lane] / d + r + bias[lane];
  h[(size_t)n * COUT + lane] = (o > 0.f) ? o : expm1f(o);
}

// ---------- kNN merge + interp ----------
__global__ void knn_merge_kernel(const unsigned long long* __restrict__ part,
                                 const float* __restrict__ h,
                                 const int* __restrict__ kptr,
                                 float* __restrict__ out, int Nx_, int Ny_) {
  int kk = *kptr;
  if (kk > 3) return;  // generic path handles
  kk = kk < 1 ? 1 : kk;
  int lane = threadIdx.x & 63;
  int qy = (int)((blockIdx.x * blockDim.x + threadIdx.x) >> 6);
  if (qy >= Ny_) return;

  unsigned long long key = ~0ull;
  if (lane < 3 * NSPLIT) {
    key = part[((size_t)(lane / 3) * Ny_ + qy) * 3 + (lane % 3)];
  }

  float num = 0.f, den = 0.f;
  for (int i = 0; i < kk; i++) {
    unsigned long long m = wmin64(key);
    if (key == m) key = ~0ull;
    unsigned u = (unsigned)(m >> 32);
    int idx = (int)(m & 0xffffffffu);
    idx = (idx < 0 || idx >= Nx_) ? 0 : idx;
    float d2 = f32_unorderable(u);
    float w = 1.f / fmaxf(d2, 1e-16f);
    num = fmaf(w, h[(size_t)idx * COUT + lane], num);
    den += w;
  }
  out[(size_t)qy * COUT + lane] = num / den;
}

// ---------- generic k>3 fallback ----------
__global__ void knn_generic_kernel(const float* __restrict__ h,
                                   const float4* __restrict__ pxp4,
                                   const float* __restrict__ pxb,
                                   const float* __restrict__ pos_y,
                                   const int* __restrict__ batch_y,
                                   const int* __restrict__ kptr,
                                   float* __restrict__ out,
                                   int Nx_, int Ny_) {
  int kk = *kptr;
  if (kk <= 3) return;  // fast path handles
  kk = kk > 8 ? 8 : kk;
  int lane = threadIdx.x & 63;
  int yy = (int)((blockIdx.x * blockDim.x + threadIdx.x) >> 6);
  if (yy >= Ny_) return;

  float q0 = pos_y[yy * 3 + 0], q1 = pos_y[yy * 3 + 1], q2 = pos_y[yy * 3 + 2];
  float q3 = (float)batch_y[yy] * BM;
  float py2t = qnorm4(q0, q1, q2, q3);

  unsigned long long best[8];
#pragma unroll
  for (int j = 0; j < 8; j++) best[j] = ~0ull;

  for (int t0 = 0; t0 < Nx_; t0 += 64) {
    int t = t0 + lane;
    unsigned long long key = ~0ull;
    if (t < Nx_) {
      float d2 = dist2(q0, q1, q2, q3, py2t, pxp4[t], pxb[t]);
      key = (((unsigned long long)f32_orderable(d2)) << 32) | (unsigned)t;
    }
    if (key < best[7]) {
#pragma unroll
      for (int j = 0; j < 8; j++) {
        unsigned long long mn = key < best[j] ? key : best[j];
        unsigned long long mx = key < best[j] ? best[j] : key;
        best[j] = mn;
        key = mx;
      }
    }
  }

  float num = 0.f, den = 0.f;
  for (int j = 0; j < kk; j++) {
    unsigned long long m = wmin64(best[0]);
    if (best[0] == m) {
#pragma unroll
      for (int t = 0; t < 7; t++) best[t] = best[t + 1];
      best[7] = ~0ull;
    }
    unsigned u = (unsigned)(m >> 32);
    int idx = (int)(m & 0xffffffffu);
    idx = (idx < 0 || idx >= Nx_) ? 0 : idx;
    float d2 = f32_unorderable(u);
    float w = 1.f / fmaxf(d2, 1e-16f);
    num = fmaf(w, h[(size_t)idx * COUT + lane], num);
    den += w;
  }
  out[(size_t)yy * COUT + lane] = num / den;
}

extern "C" void kernel_launch(void* const* d_in, const int* in_sizes, int n_in,
                              void* d_out, int out_size, void* d_ws, size_t ws_size,
                              hipStream_t stream) {
  const float* x = (const float*)d_in[0];
  const float* pos_x = (const float*)d_in[1];
  const float* pos_y = (const float*)d_in[2];
  const int* eidx = (const int*)d_in[3];
  const float* pseudo = (const float*)d_in[4];
  const int* batch_x = (const int*)d_in[5];
  const int* batch_y = (const int*)d_in[6];
  const float* W = (const float*)d_in[7];   // [125,64,64]
  const float* root = (const float*)d_in[8];
  const float* bias = (const float*)d_in[9];
  const int* kptr = (const int*)d_in[10];

  int Nx = in_sizes[0] / CIN;
  int Ny = in_sizes[2] / 3;
  int E = in_sizes[3] / 2;

  int csize = ((Nx + NSPLIT - 1) / NSPLIT + 255) & ~255;
  if (csize < 256) csize = 256;

  // ws layout: acc[Nx*64]f | deg[Nx]f | h[Nx*64]f | pxp4[Nx]float4 | pxb[Nx]f |
  //   xbf[Nx*64]u16 | wbf[125*4096]u16 | xw[125*Nx*64]u16 |
  //   vpart[NSPLIT*Ny*3]f | part[NSPLIT*Ny*3]u64
  float* acc = (float*)d_ws;
  float* deg = acc + (size_t)Nx * COUT;
  float* h = deg + Nx;
  float4* pxp4 = (float4*)(h + (size_t)Nx * COUT);
  float* pxb = (float*)(pxp4 + Nx);
  unsigned short* xbf = (unsigned short*)(pxb + Nx);
  unsigned short* wbf = xbf + (size_t)Nx * CIN;
  unsigned short* xw = wbf + (size_t)KTOT * CIN * COUT;
  float* vpart = (float*)(xw + (size_t)Nx * KTOT * COUT);
  uintptr_t paddr = (uintptr_t)(vpart + (size_t)NSPLIT * Ny * 3);
  paddr = (paddr + 7) & ~(uintptr_t)7;
  unsigned long long* part = (unsigned long long*)paddr;

  float* out = (float*)d_out;

  int n4 = Nx * CIN / 4;
  int nb_cvtx = (n4 + 255) / 256;
  int nb_pack = (Nx + 255) / 256;
  int nz4 = (Nx * COUT + Nx) / 4;          // acc+deg floats / 4 (Nx*65 % 4 == 0)
  int nb_zero = (nz4 + 255) / 256;
  int nqb = (Ny + 255) / 256;
  int nb_knn = nqb * NSPLIT;
  int nxb = (Nx + 63) / 64;
  int nb_xw = nxb * KTOT;
  int nb_edge = (int)(((size_t)E * WAVE + 255) / 256);

  // P: zero | cvtx | cvtw | pack
  pre_kernel<<<nb_zero + nb_cvtx + KTOT + nb_pack, 256, 0, stream>>>(
      x, xbf, n4, W, wbf, pos_x, batch_x, pxp4, pxb, Nx, acc, nz4, nb_zero,
      nb_cvtx);

  // Q: XCD-safe interleaved knn_val | xw_mfma
  {
    int total = nb_knn + nb_xw;
    int S = total / nb_knn;
    if (S < 2) S = 2;
    phaseQ_kernel<<<total, 256, 0, stream>>>(
        pxp4, pxb, pos_y, batch_y, kptr, vpart, Ny, csize, nb_knn, nqb, S,
        xbf, wbf, xw, Nx, nxb);
  }

  // R: XCD-safe interleaved knn_rec | edge_sum
  {
    int total = nb_knn + nb_edge;
    int S = total / nb_knn;
    if (S < 2) S = 2;
    phaseR_kernel<<<total, 256, 0, stream>>>(
        vpart, pxp4, pxb, pos_y, batch_y, kptr, part, Ny, csize, nb_knn, nqb, S,
        eidx, pseudo, xw, acc, deg, E, Nx);
  }

  {
    int blocks = (Nx * WAVE + 255) / 256;
    node_finish_kernel<<<blocks, 256, 0, stream>>>(x, root, bias, acc, deg, h, Nx);
  }
  {
    int blocks = (Ny * WAVE + 255) / 256;
    knn_merge_kernel<<<blocks, 256, 0, stream>>>(part, h, kptr, out, Nx, Ny);
    knn_generic_kernel<<<blocks, 256, 0, stream>>>(h, pxp4, pxb, pos_y, batch_y,
                                                   kptr, out, Nx, Ny);
  }
}

// Round 18
// 102.854 us; speedup vs baseline: 1.8178x; 1.4310x over previous
//
#include <hip/hip_runtime.h>
#include <stdint.h>

#define WAVE 64
#define CIN 64
#define COUT 64
#define KS 5
#define KTOT 125   // 5^3
#define NSPLIT 16  // kNN candidate splits (3*NSPLIT must be <= 64)
#define KB4 32     // ceil(125/4) k-groups for batched xw
#define BM 1e5f    // batch fold scale: BM*BM = 1e10 (reference mismatch penalty)

typedef __attribute__((ext_vector_type(8))) short short8v;  // 8 bf16 = 4 VGPRs
typedef __attribute__((ext_vector_type(4))) float f32x4;

__device__ inline unsigned long long wmin64(unsigned long long v) {
#pragma unroll
  for (int o = 32; o >= 1; o >>= 1) {
    unsigned long long u = __shfl_xor(v, o, 64);
    v = (u < v) ? u : v;
  }
  return v;
}

__device__ inline unsigned f32_orderable(float f) {
  unsigned fb = __float_as_uint(f);
  return (fb & 0x80000000u) ? ~fb : (fb | 0x80000000u);
}
__device__ inline float f32_unorderable(unsigned u) {
  unsigned fb = (u & 0x80000000u) ? (u & 0x7fffffffu) : ~u;
  return __uint_as_float(fb);
}

__device__ inline unsigned short f2bf(float f) {  // RNE
  unsigned u = __float_as_uint(f);
  unsigned r = (u + 0x7fffu + ((u >> 16) & 1u)) >> 16;
  return (unsigned short)r;
}
__device__ inline float bf2f(unsigned short v) {
  return __uint_as_float(((unsigned)v) << 16);
}

// ---- shared, contraction-proof d2 helpers (bit-identical everywhere) ----
__device__ __forceinline__ float qnorm4(float q0, float q1, float q2, float q3) {
  return fmaf(q0, q0, fmaf(q1, q1, fmaf(q2, q2, q3 * q3)));
}
__device__ __forceinline__ float dist2(float q0, float q1, float q2, float q3,
                                       float py2t, float4 c, float c3) {
  float dot = fmaf(q0, c.x, fmaf(q1, c.y, fmaf(q2, c.z, q3 * c3)));
  return fmaf(-2.f, dot, py2t + c.w);
}

__device__ inline void edge_basis(const float* __restrict__ pseudo, int e,
                                  float bas[8], int kidx[8]) {
  float v0 = pseudo[e * 3 + 0] * (float)(KS - 1);
  float v1 = pseudo[e * 3 + 1] * (float)(KS - 1);
  float v2 = pseudo[e * 3 + 2] * (float)(KS - 1);
  float l0 = floorf(v0), l1 = floorf(v1), l2 = floorf(v2);
  float f0 = v0 - l0, f1 = v1 - l1, f2 = v2 - l2;
  int i0 = (int)l0, i1 = (int)l1, i2 = (int)l2;
#pragma unroll
  for (int s = 0; s < 8; s++) {
    int b0 = s & 1, b1 = (s >> 1) & 1, b2 = (s >> 2) & 1;
    float bb = (b0 ? f0 : 1.f - f0) * (b1 ? f1 : 1.f - f1) * (b2 ? f2 : 1.f - f2);
    int j0 = i0 + b0; j0 = j0 < 0 ? 0 : (j0 > KS - 1 ? KS - 1 : j0);
    int j1 = i1 + b1; j1 = j1 < 0 ? 0 : (j1 > KS - 1 ? KS - 1 : j1);
    int j2 = i2 + b2; j2 = j2 < 0 ? 0 : (j2 > KS - 1 ? KS - 1 : j2);
    bas[s] = bb;
    kidx[s] = j0 + KS * j1 + KS * KS * j2;
  }
}

// ============ P: fused preamble — zero(acc,deg) | cvtx | cvtw | pack_posx ============
__global__ __launch_bounds__(256) void pre_kernel(
    const float* __restrict__ x, unsigned short* __restrict__ xbf, int n4,
    const float* __restrict__ Wf, unsigned short* __restrict__ wbf,
    const float* __restrict__ pos_x, const int* __restrict__ batch_x,
    float4* __restrict__ pxp4, float* __restrict__ pxb, int Nx_,
    float* __restrict__ zbase, int nz4, int nb_zero, int nb_cvtx) {
  __shared__ float L[64][68];
  int bid = blockIdx.x;
  int tid = threadIdx.x;

  if (bid < nb_zero) {  // ---- zero acc+deg ----
    int i = bid * 256 + tid;
    if (i < nz4) *(float4*)&zbase[i * 4] = make_float4(0.f, 0.f, 0.f, 0.f);
    return;
  }
  bid -= nb_zero;
  if (bid < nb_cvtx) {  // ---- cvtx ----
    int i = bid * 256 + tid;
    if (i >= n4) return;
    float4 v = *(const float4*)&x[i * 4];
    *(ushort4*)&xbf[i * 4] =
        make_ushort4(f2bf(v.x), f2bf(v.y), f2bf(v.z), f2bf(v.w));
    return;
  }
  bid -= nb_cvtx;
  if (bid < KTOT) {  // ---- cvtw ----
    int k = bid;
    {
      int i = tid >> 2, o0 = (tid & 3) * 16;
      const float* src = Wf + (size_t)k * 4096 + i * 64 + o0;
      float4 a = *(const float4*)src;
      float4 b = *(const float4*)(src + 4);
      float4 c = *(const float4*)(src + 8);
      float4 d = *(const float4*)(src + 12);
      *(float4*)&L[i][o0 + 0] = a;
      *(float4*)&L[i][o0 + 4] = b;
      *(float4*)&L[i][o0 + 8] = c;
      *(float4*)&L[i][o0 + 12] = d;
    }
    __syncthreads();
    int o = tid >> 2, i0 = (tid & 3) * 16;
    unsigned short* dst = wbf + (size_t)k * 4096 + o * 64 + i0;
#pragma unroll
    for (int g = 0; g < 4; g++) {
      *(ushort4*)&dst[g * 4] =
          make_ushort4(f2bf(L[i0 + g * 4 + 0][o]), f2bf(L[i0 + g * 4 + 1][o]),
                       f2bf(L[i0 + g * 4 + 2][o]), f2bf(L[i0 + g * 4 + 3][o]));
    }
    return;
  }
  bid -= KTOT;
  {  // ---- pack_posx ----
    int t = bid * 256 + tid;
    if (t >= Nx_) return;
    float a0 = pos_x[t * 3 + 0], a1 = pos_x[t * 3 + 1], a2 = pos_x[t * 3 + 2];
    float bm = (float)batch_x[t] * BM;
    pxp4[t] = make_float4(a0, a1, a2, qnorm4(a0, a1, a2, bm));
    pxb[t] = bm;
  }
}

// ============ Q: knn_val (blocks first) | xw_mfma 4-k batched ============
__global__ __launch_bounds__(256) void phaseQ_kernel(
    const float4* __restrict__ pxp4, const float* __restrict__ pxb,
    const float* __restrict__ pos_y, const int* __restrict__ batch_y,
    const int* __restrict__ kptr, float* __restrict__ vpart,
    int Ny_, int csize, int nb_knn, int nqb,
    const unsigned short* __restrict__ xbf,
    const unsigned short* __restrict__ wbf,
    unsigned short* __restrict__ xw, int Nx_, int nxb) {
  __shared__ char smem[8192];
  int bid = blockIdx.x;
  int tid = threadIdx.x;

  if (bid < nb_knn) {  // ---- knn_val (verbatim round-15 math) ----
    if (*kptr > 3) return;
    float4* lc = (float4*)smem;
    float* lb = (float*)(smem + 4096);
    const float FINF = __uint_as_float(0x7f800000u);

    int split = bid / nqb;
    int qy = (bid % nqb) * 256 + tid;
    int base0 = split * csize;

    int qc = qy < Ny_ ? qy : Ny_ - 1;
    float q0 = pos_y[qc * 3 + 0], q1 = pos_y[qc * 3 + 1], q2 = pos_y[qc * 3 + 2];
    float q3 = (float)batch_y[qc] * BM;
    float py2t = qnorm4(q0, q1, q2, q3);

    float b0 = FINF, b1 = FINF, b2 = FINF;

    for (int tb = 0; tb < csize; tb += 256) {
      int t = base0 + tb + tid;
      float4 cv;
      float cb;
      if (t < Nx_) {
        cv = pxp4[t];
        cb = pxb[t];
      } else {
        cv = make_float4(0.f, 0.f, 0.f, FINF);
        cb = 0.f;
      }
      __syncthreads();
      lc[tid] = cv;
      lb[tid] = cb;
      __syncthreads();

#pragma unroll 4
      for (int j = 0; j < 256; j++) {
        float d2 = dist2(q0, q1, q2, q3, py2t, lc[j], lb[j]);
        float n0 = fminf(d2, b0);
        float n1 = fminf(fmaxf(d2, b0), b1);
        float n2 = fminf(fmaxf(d2, b1), b2);
        b0 = n0; b1 = n1; b2 = n2;
      }
    }

    if (qy < Ny_) {
      float* vp = vpart + ((size_t)split * Ny_ + qy) * 3;
      vp[0] = b0;
      vp[1] = b1;
      vp[2] = b2;
    }
    return;
  }

  // ---- xw_mfma, 4 k's per block (A-fragments reused) ----
  {
    int b = bid - nb_knn;
    int n0 = (b % nxb) * 64;
    int kg4 = b / nxb;
    unsigned short(*Sm)[64] = (unsigned short(*)[64])smem;

    int w = tid >> 6, lane = tid & 63;
    int lr = lane & 15, kg = lane >> 4;
    int rA = n0 + w * 16 + lr;
    if (rA >= Nx_) rA = Nx_ - 1;

    short8v a0 = *(const short8v*)&xbf[(size_t)rA * CIN + kg * 8];
    short8v a1 = *(const short8v*)&xbf[(size_t)rA * CIN + 32 + kg * 8];

    for (int kk4 = 0; kk4 < 4; kk4++) {
      int k = kg4 * 4 + kk4;
      if (k >= KTOT) break;  // uniform per block -> barrier-safe
      const unsigned short* wb = wbf + (size_t)k * 4096;
#pragma unroll
      for (int ct = 0; ct < 4; ct++) {
        int col = ct * 16 + lr;
        short8v b0 = *(const short8v*)&wb[col * 64 + kg * 8];
        short8v b1 = *(const short8v*)&wb[col * 64 + 32 + kg * 8];
        f32x4 c = {0.f, 0.f, 0.f, 0.f};
        c = __builtin_amdgcn_mfma_f32_16x16x32_bf16(a0, b0, c, 0, 0, 0);
        c = __builtin_amdgcn_mfma_f32_16x16x32_bf16(a1, b1, c, 0, 0, 0);
#pragma unroll
        for (int r = 0; r < 4; r++) {
          Sm[w * 16 + kg * 4 + r][ct * 16 + lr] = f2bf(c[r]);
        }
      }
      __syncthreads();  // stage complete

#pragma unroll
      for (int round = 0; round < 2; round++) {
        int rr = (tid >> 3) + round * 32;
        int ch = (tid & 7) * 8;
        int grow = n0 + rr;
        if (grow < Nx_) {
          uint4 v = *(const uint4*)&Sm[rr][ch];
          *(uint4*)&xw[((size_t)k * Nx_ + grow) * COUT + ch] = v;
        }
      }
      __syncthreads();  // store reads done before next k overwrites LDS
    }
  }
}

// ============ R: knn_rec (blocks first) | edge_sum ============
__global__ __launch_bounds__(256) void phaseR_kernel(
    const float* __restrict__ vpart,
    const float4* __restrict__ pxp4, const float* __restrict__ pxb,
    const float* __restrict__ pos_y, const int* __restrict__ batch_y,
    const int* __restrict__ kptr, unsigned long long* __restrict__ part,
    int Ny_, int csize, int nb_knn, int nqb,
    const int* __restrict__ ei, const float* __restrict__ pseudo,
    const unsigned short* __restrict__ xw, float* __restrict__ acc,
    float* __restrict__ deg, int E_, int Nx_) {
  __shared__ char smem[5120];
  int bid = blockIdx.x;
  int tid = threadIdx.x;

  if (bid < nb_knn) {  // ---- knn_rec (verbatim round-15 math) ----
    int kk = *kptr;
    if (kk > 3) return;
    kk = kk < 1 ? 1 : kk;
    float4* lc = (float4*)smem;
    float* lb = (float*)(smem + 4096);
    const float FINF = __uint_as_float(0x7f800000u);

    int split = bid / nqb;
    int qy = (bid % nqb) * 256 + tid;
    int base0 = split * csize;

    int qc = qy < Ny_ ? qy : Ny_ - 1;
    float q0 = pos_y[qc * 3 + 0], q1 = pos_y[qc * 3 + 1], q2 = pos_y[qc * 3 + 2];
    float q3 = (float)batch_y[qc] * BM;
    float py2t = qnorm4(q0, q1, q2, q3);

    float t0v = FINF, t1v = FINF, t2v = FINF;
#pragma unroll
    for (int s = 0; s < NSPLIT; s++) {
      const float* vp = vpart + ((size_t)s * Ny_ + qc) * 3;
#pragma unroll
      for (int r = 0; r < 3; r++) {
        float v = vp[r];
        float n0 = fminf(v, t0v);
        float n1 = fminf(fmaxf(v, t0v), t1v);
        float n2 = fminf(fmaxf(v, t1v), t2v);
        t0v = n0; t1v = n1; t2v = n2;
      }
    }
    float thr = kk == 1 ? t0v : (kk == 2 ? t1v : t2v);

    unsigned long long k0 = ~0ull, k1 = ~0ull, k2 = ~0ull;

    for (int tb = 0; tb < csize; tb += 256) {
      int t = base0 + tb + tid;
      float4 cv;
      float cb;
      if (t < Nx_) {
        cv = pxp4[t];
        cb = pxb[t];
      } else {
        cv = make_float4(0.f, 0.f, 0.f, FINF);
        cb = 0.f;
      }
      __syncthreads();
      lc[tid] = cv;
      lb[tid] = cb;
      __syncthreads();

#pragma unroll 4
      for (int j = 0; j < 256; j++) {
        float d2 = dist2(q0, q1, q2, q3, py2t, lc[j], lb[j]);
        if (d2 <= thr) {
          unsigned long long key =
              (((unsigned long long)f32_orderable(d2)) << 32) |
              (unsigned)(base0 + tb + j);
          {
            bool lt = key < k0;
            unsigned long long nv = lt ? key : k0;
            unsigned long long xv = lt ? k0 : key;
            k0 = nv; key = xv;
          }
          {
            bool lt = key < k1;
            unsigned long long nv = lt ? key : k1;
            unsigned long long xv = lt ? k1 : key;
            k1 = nv; key = xv;
          }
          k2 = key < k2 ? key : k2;
        }
      }
    }

    if (qy < Ny_) {
      unsigned long long* pp = part + ((size_t)split * Ny_ + qy) * 3;
      pp[0] = k0;
      pp[1] = k1;
      pp[2] = k2;
    }
    return;
  }

  // ---- edge_sum (verbatim) ----
  {
    int b = bid - nb_knn;
    int lane = tid & 63;
    int e = (int)(((size_t)b * 256 + tid) >> 6);
    if (e >= E_) return;
    int src = ei[e];
    int dst = ei[E_ + e];
    float bas[8];
    int kidx[8];
    edge_basis(pseudo, e, bas, kidx);

    float y = 0.f;
#pragma unroll
    for (int s = 0; s < 8; s++) {
      y = fmaf(bas[s], bf2f(xw[((size_t)kidx[s] * Nx_ + src) * COUT + lane]), y);
    }
    atomicAdd(&acc[(size_t)dst * COUT + lane], y);
    if (lane == 0) atomicAdd(&deg[dst], 1.f);
  }
}

// ---------- node finish ----------
__global__ void node_finish_kernel(const float* __restrict__ x,
                                   const float* __restrict__ root,
                                   const float* __restrict__ bias,
                                   const float* __restrict__ acc,
                                   const float* __restrict__ deg,
                                   float* __restrict__ h, int Nx_) {
  int lane = threadIdx.x & 63;
  int n = (int)((blockIdx.x * blockDim.x + threadIdx.x) >> 6);
  if (n >= Nx_) return;
  float xs = x[(size_t)n * CIN + lane];
  float r = 0.f;
#pragma unroll 4
  for (int i = 0; i < CIN; i++) {
    float xv = __shfl(xs, i, 64);
    r = fmaf(xv, root[i * COUT + lane], r);
  }
  float d = deg[n];
  d = d > 1.f ? d : 1.f;
  float o = acc[(size_t)n * COUT + lane] / d + r + bias[lane];
  h[(size_t)n * COUT + lane] = (o > 0.f) ? o : expm1f(o);
}

// ---------- kNN merge + interp ----------
__global__ void knn_merge_kernel(const unsigned long long* __restrict__ part,
                                 const float* __restrict__ h,
                                 const int* __restrict__ kptr,
                                 float* __restrict__ out, int Nx_, int Ny_) {
  int kk = *kptr;
  if (kk > 3) return;  // generic path handles
  kk = kk < 1 ? 1 : kk;
  int lane = threadIdx.x & 63;
  int qy = (int)((blockIdx.x * blockDim.x + threadIdx.x) >> 6);
  if (qy >= Ny_) return;

  unsigned long long key = ~0ull;
  if (lane < 3 * NSPLIT) {
    key = part[((size_t)(lane / 3) * Ny_ + qy) * 3 + (lane % 3)];
  }

  float num = 0.f, den = 0.f;
  for (int i = 0; i < kk; i++) {
    unsigned long long m = wmin64(key);
    if (key == m) key = ~0ull;
    unsigned u = (unsigned)(m >> 32);
    int idx = (int)(m & 0xffffffffu);
    idx = (idx < 0 || idx >= Nx_) ? 0 : idx;
    float d2 = f32_unorderable(u);
    float w = 1.f / fmaxf(d2, 1e-16f);
    num = fmaf(w, h[(size_t)idx * COUT + lane], num);
    den += w;
  }
  out[(size_t)qy * COUT + lane] = num / den;
}

// ---------- generic k>3 fallback ----------
__global__ void knn_generic_kernel(const float* __restrict__ h,
                                   const float4* __restrict__ pxp4,
                                   const float* __restrict__ pxb,
                                   const float* __restrict__ pos_y,
                                   const int* __restrict__ batch_y,
                                   const int* __restrict__ kptr,
                                   float* __restrict__ out,
                                   int Nx_, int Ny_) {
  int kk = *kptr;
  if (kk <= 3) return;  // fast path handles
  kk = kk > 8 ? 8 : kk;
  int lane = threadIdx.x & 63;
  int yy = (int)((blockIdx.x * blockDim.x + threadIdx.x) >> 6);
  if (yy >= Ny_) return;

  float q0 = pos_y[yy * 3 + 0], q1 = pos_y[yy * 3 + 1], q2 = pos_y[yy * 3 + 2];
  float q3 = (float)batch_y[yy] * BM;
  float py2t = qnorm4(q0, q1, q2, q3);

  unsigned long long best[8];
#pragma unroll
  for (int j = 0; j < 8; j++) best[j] = ~0ull;

  for (int t0 = 0; t0 < Nx_; t0 += 64) {
    int t = t0 + lane;
    unsigned long long key = ~0ull;
    if (t < Nx_) {
      float d2 = dist2(q0, q1, q2, q3, py2t, pxp4[t], pxb[t]);
      key = (((unsigned long long)f32_orderable(d2)) << 32) | (unsigned)t;
    }
    if (key < best[7]) {
#pragma unroll
      for (int j = 0; j < 8; j++) {
        unsigned long long mn = key < best[j] ? key : best[j];
        unsigned long long mx = key < best[j] ? best[j] : key;
        best[j] = mn;
        key = mx;
      }
    }
  }

  float num = 0.f, den = 0.f;
  for (int j = 0; j < kk; j++) {
    unsigned long long m = wmin64(best[0]);
    if (best[0] == m) {
#pragma unroll
      for (int t = 0; t < 7; t++) best[t] = best[t + 1];
      best[7] = ~0ull;
    }
    unsigned u = (unsigned)(m >> 32);
    int idx = (int)(m & 0xffffffffu);
    idx = (idx < 0 || idx >= Nx_) ? 0 : idx;
    float d2 = f32_unorderable(u);
    float w = 1.f / fmaxf(d2, 1e-16f);
    num = fmaf(w, h[(size_t)idx * COUT + lane], num);
    den += w;
  }
  out[(size_t)yy * COUT + lane] = num / den;
}

extern "C" void kernel_launch(void* const* d_in, const int* in_sizes, int n_in,
                              void* d_out, int out_size, void* d_ws, size_t ws_size,
                              hipStream_t stream) {
  const float* x = (const float*)d_in[0];
  const float* pos_x = (const float*)d_in[1];
  const float* pos_y = (const float*)d_in[2];
  const int* eidx = (const int*)d_in[3];
  const float* pseudo = (const float*)d_in[4];
  const int* batch_x = (const int*)d_in[5];
  const int* batch_y = (const int*)d_in[6];
  const float* W = (const float*)d_in[7];   // [125,64,64]
  const float* root = (const float*)d_in[8];
  const float* bias = (const float*)d_in[9];
  const int* kptr = (const int*)d_in[10];

  int Nx = in_sizes[0] / CIN;
  int Ny = in_sizes[2] / 3;
  int E = in_sizes[3] / 2;

  int csize = ((Nx + NSPLIT - 1) / NSPLIT + 255) & ~255;
  if (csize < 256) csize = 256;

  // ws layout: acc[Nx*64]f | deg[Nx]f | h[Nx*64]f | pxp4[Nx]float4 | pxb[Nx]f |
  //   xbf[Nx*64]u16 | wbf[125*4096]u16 | xw[125*Nx*64]u16 |
  //   vpart[NSPLIT*Ny*3]f | part[NSPLIT*Ny*3]u64
  float* acc = (float*)d_ws;
  float* deg = acc + (size_t)Nx * COUT;
  float* h = deg + Nx;
  float4* pxp4 = (float4*)(h + (size_t)Nx * COUT);
  float* pxb = (float*)(pxp4 + Nx);
  unsigned short* xbf = (unsigned short*)(pxb + Nx);
  unsigned short* wbf = xbf + (size_t)Nx * CIN;
  unsigned short* xw = wbf + (size_t)KTOT * CIN * COUT;
  float* vpart = (float*)(xw + (size_t)Nx * KTOT * COUT);
  uintptr_t paddr = (uintptr_t)(vpart + (size_t)NSPLIT * Ny * 3);
  paddr = (paddr + 7) & ~(uintptr_t)7;
  unsigned long long* part = (unsigned long long*)paddr;

  float* out = (float*)d_out;

  int n4 = Nx * CIN / 4;
  int nb_cvtx = (n4 + 255) / 256;
  int nb_pack = (Nx + 255) / 256;
  int nz4 = (Nx * COUT + Nx) / 4;  // acc+deg floats / 4 (Nx*65 % 4 == 0)
  int nb_zero = (nz4 + 255) / 256;
  int nqb = (Ny + 255) / 256;
  int nb_knn = nqb * NSPLIT;
  int nxb = (Nx + 63) / 64;
  int nkg4 = (KTOT + 3) / 4;       // 32
  int nb_xw = nxb * nkg4;
  int nb_edge = (int)(((size_t)E * WAVE + 255) / 256);

  // P: zero | cvtx | cvtw | pack
  pre_kernel<<<nb_zero + nb_cvtx + KTOT + nb_pack, 256, 0, stream>>>(
      x, xbf, n4, W, wbf, pos_x, batch_x, pxp4, pxb, Nx, acc, nz4, nb_zero,
      nb_cvtx);

  // Q: knn_val first | xw_mfma 4-k batched
  phaseQ_kernel<<<nb_knn + nb_xw, 256, 0, stream>>>(
      pxp4, pxb, pos_y, batch_y, kptr, vpart, Ny, csize, nb_knn, nqb,
      xbf, wbf, xw, Nx, nxb);

  // R: knn_rec first | edge_sum
  phaseR_kernel<<<nb_knn + nb_edge, 256, 0, stream>>>(
      vpart, pxp4, pxb, pos_y, batch_y, kptr, part, Ny, csize, nb_knn, nqb,
      eidx, pseudo, xw, acc, deg, E, Nx);

  {
    int blocks = (Nx * WAVE + 255) / 256;
    node_finish_kernel<<<blocks, 256, 0, stream>>>(x, root, bias, acc, deg, h, Nx);
  }
  {
    int blocks = (Ny * WAVE + 255) / 256;
    knn_merge_kernel<<<blocks, 256, 0, stream>>>(part, h, kptr, out, Nx, Ny);
    knn_generic_kernel<<<blocks, 256, 0, stream>>>(h, pxp4, pxb, pos_y, batch_y,
                                                   kptr, out, Nx, Ny);
  }
}

// Round 20
// 98.647 us; speedup vs baseline: 1.8954x; 1.0426x over previous
//
#include <hip/hip_runtime.h>
#include <stdint.h>

#define WAVE 64
#define CIN 64
#define COUT 64
#define KS 5
#define KTOT 125   // 5^3
#define NSPLIT 16  // kNN candidate splits (3*NSPLIT must be <= 64)
#define BM 1e5f    // batch fold scale: BM*BM = 1e10 (reference mismatch penalty)

typedef __attribute__((ext_vector_type(8))) short short8v;  // 8 bf16 = 4 VGPRs
typedef __attribute__((ext_vector_type(4))) float f32x4;
typedef __attribute__((ext_vector_type(4))) unsigned uint4v;  // native vec for nt builtins

__device__ inline unsigned long long wmin64(unsigned long long v) {
#pragma unroll
  for (int o = 32; o >= 1; o >>= 1) {
    unsigned long long u = __shfl_xor(v, o, 64);
    v = (u < v) ? u : v;
  }
  return v;
}

__device__ inline unsigned f32_orderable(float f) {
  unsigned fb = __float_as_uint(f);
  return (fb & 0x80000000u) ? ~fb : (fb | 0x80000000u);
}
__device__ inline float f32_unorderable(unsigned u) {
  unsigned fb = (u & 0x80000000u) ? (u & 0x7fffffffu) : ~u;
  return __uint_as_float(fb);
}

__device__ inline unsigned short f2bf(float f) {  // RNE
  unsigned u = __float_as_uint(f);
  unsigned r = (u + 0x7fffu + ((u >> 16) & 1u)) >> 16;
  return (unsigned short)r;
}
__device__ inline float bf2f(unsigned short v) {
  return __uint_as_float(((unsigned)v) << 16);
}

// ---- shared, contraction-proof d2 helpers (bit-identical everywhere) ----
__device__ __forceinline__ float qnorm4(float q0, float q1, float q2, float q3) {
  return fmaf(q0, q0, fmaf(q1, q1, fmaf(q2, q2, q3 * q3)));
}
__device__ __forceinline__ float dist2(float q0, float q1, float q2, float q3,
                                       float py2t, float4 c, float c3) {
  float dot = fmaf(q0, c.x, fmaf(q1, c.y, fmaf(q2, c.z, q3 * c3)));
  return fmaf(-2.f, dot, py2t + c.w);
}

__device__ inline void edge_basis(const float* __restrict__ pseudo, int e,
                                  float bas[8], int kidx[8]) {
  float v0 = pseudo[e * 3 + 0] * (float)(KS - 1);
  float v1 = pseudo[e * 3 + 1] * (float)(KS - 1);
  float v2 = pseudo[e * 3 + 2] * (float)(KS - 1);
  float l0 = floorf(v0), l1 = floorf(v1), l2 = floorf(v2);
  float f0 = v0 - l0, f1 = v1 - l1, f2 = v2 - l2;
  int i0 = (int)l0, i1 = (int)l1, i2 = (int)l2;
#pragma unroll
  for (int s = 0; s < 8; s++) {
    int b0 = s & 1, b1 = (s >> 1) & 1, b2 = (s >> 2) & 1;
    float bb = (b0 ? f0 : 1.f - f0) * (b1 ? f1 : 1.f - f1) * (b2 ? f2 : 1.f - f2);
    int j0 = i0 + b0; j0 = j0 < 0 ? 0 : (j0 > KS - 1 ? KS - 1 : j0);
    int j1 = i1 + b1; j1 = j1 < 0 ? 0 : (j1 > KS - 1 ? KS - 1 : j1);
    int j2 = i2 + b2; j2 = j2 < 0 ? 0 : (j2 > KS - 1 ? KS - 1 : j2);
    bas[s] = bb;
    kidx[s] = j0 + KS * j1 + KS * KS * j2;
  }
}

// ============ P: fused preamble — zero(acc,deg) | cvtx | cvtw | pack_posx ============
__global__ __launch_bounds__(256) void pre_kernel(
    const float* __restrict__ x, unsigned short* __restrict__ xbf, int n4,
    const float* __restrict__ Wf, unsigned short* __restrict__ wbf,
    const float* __restrict__ pos_x, const int* __restrict__ batch_x,
    float4* __restrict__ pxp4, float* __restrict__ pxb, int Nx_,
    float* __restrict__ zbase, int nz4, int nb_zero, int nb_cvtx) {
  __shared__ float L[64][68];
  int bid = blockIdx.x;
  int tid = threadIdx.x;

  if (bid < nb_zero) {  // ---- zero acc+deg ----
    int i = bid * 256 + tid;
    if (i < nz4) *(float4*)&zbase[i * 4] = make_float4(0.f, 0.f, 0.f, 0.f);
    return;
  }
  bid -= nb_zero;
  if (bid < nb_cvtx) {  // ---- cvtx ----
    int i = bid * 256 + tid;
    if (i >= n4) return;
    float4 v = *(const float4*)&x[i * 4];
    *(ushort4*)&xbf[i * 4] =
        make_ushort4(f2bf(v.x), f2bf(v.y), f2bf(v.z), f2bf(v.w));
    return;
  }
  bid -= nb_cvtx;
  if (bid < KTOT) {  // ---- cvtw ----
    int k = bid;
    {
      int i = tid >> 2, o0 = (tid & 3) * 16;
      const float* src = Wf + (size_t)k * 4096 + i * 64 + o0;
      float4 a = *(const float4*)src;
      float4 b = *(const float4*)(src + 4);
      float4 c = *(const float4*)(src + 8);
      float4 d = *(const float4*)(src + 12);
      *(float4*)&L[i][o0 + 0] = a;
      *(float4*)&L[i][o0 + 4] = b;
      *(float4*)&L[i][o0 + 8] = c;
      *(float4*)&L[i][o0 + 12] = d;
    }
    __syncthreads();
    int o = tid >> 2, i0 = (tid & 3) * 16;
    unsigned short* dst = wbf + (size_t)k * 4096 + o * 64 + i0;
#pragma unroll
    for (int g = 0; g < 4; g++) {
      *(ushort4*)&dst[g * 4] =
          make_ushort4(f2bf(L[i0 + g * 4 + 0][o]), f2bf(L[i0 + g * 4 + 1][o]),
                       f2bf(L[i0 + g * 4 + 2][o]), f2bf(L[i0 + g * 4 + 3][o]));
    }
    return;
  }
  bid -= KTOT;
  {  // ---- pack_posx ----
    int t = bid * 256 + tid;
    if (t >= Nx_) return;
    float a0 = pos_x[t * 3 + 0], a1 = pos_x[t * 3 + 1], a2 = pos_x[t * 3 + 2];
    float bm = (float)batch_x[t] * BM;
    pxp4[t] = make_float4(a0, a1, a2, qnorm4(a0, a1, a2, bm));
    pxb[t] = bm;
  }
}

// ============ Q: knn_val (blocks first) | xw_mfma 8-k batched, nt stores ============
__global__ __launch_bounds__(256) void phaseQ_kernel(
    const float4* __restrict__ pxp4, const float* __restrict__ pxb,
    const float* __restrict__ pos_y, const int* __restrict__ batch_y,
    const int* __restrict__ kptr, float* __restrict__ vpart,
    int Ny_, int csize, int nb_knn, int nqb,
    const unsigned short* __restrict__ xbf,
    const unsigned short* __restrict__ wbf,
    unsigned short* __restrict__ xw, int Nx_, int nxb) {
  __shared__ char smem[8192];
  int bid = blockIdx.x;
  int tid = threadIdx.x;

  if (bid < nb_knn) {  // ---- knn_val (verbatim math) ----
    if (*kptr > 3) return;
    float4* lc = (float4*)smem;
    float* lb = (float*)(smem + 4096);
    const float FINF = __uint_as_float(0x7f800000u);

    int split = bid / nqb;
    int qy = (bid % nqb) * 256 + tid;
    int base0 = split * csize;

    int qc = qy < Ny_ ? qy : Ny_ - 1;
    float q0 = pos_y[qc * 3 + 0], q1 = pos_y[qc * 3 + 1], q2 = pos_y[qc * 3 + 2];
    float q3 = (float)batch_y[qc] * BM;
    float py2t = qnorm4(q0, q1, q2, q3);

    float b0 = FINF, b1 = FINF, b2 = FINF;

    for (int tb = 0; tb < csize; tb += 256) {
      int t = base0 + tb + tid;
      float4 cv;
      float cb;
      if (t < Nx_) {
        cv = pxp4[t];
        cb = pxb[t];
      } else {
        cv = make_float4(0.f, 0.f, 0.f, FINF);
        cb = 0.f;
      }
      __syncthreads();
      lc[tid] = cv;
      lb[tid] = cb;
      __syncthreads();

#pragma unroll 4
      for (int j = 0; j < 256; j++) {
        float d2 = dist2(q0, q1, q2, q3, py2t, lc[j], lb[j]);
        float n0 = fminf(d2, b0);
        float n1 = fminf(fmaxf(d2, b0), b1);
        float n2 = fminf(fmaxf(d2, b1), b2);
        b0 = n0; b1 = n1; b2 = n2;
      }
    }

    if (qy < Ny_) {
      float* vp = vpart + ((size_t)split * Ny_ + qy) * 3;
      vp[0] = b0;
      vp[1] = b1;
      vp[2] = b2;
    }
    return;
  }

  // ---- xw_mfma, 8 k's per block (A-fragments reused), non-temporal stores ----
  {
    int b = bid - nb_knn;
    int n0 = (b % nxb) * 64;
    int kg8 = b / nxb;
    unsigned short(*Sm)[64] = (unsigned short(*)[64])smem;

    int w = tid >> 6, lane = tid & 63;
    int lr = lane & 15, kg = lane >> 4;
    int rA = n0 + w * 16 + lr;
    if (rA >= Nx_) rA = Nx_ - 1;

    short8v a0 = *(const short8v*)&xbf[(size_t)rA * CIN + kg * 8];
    short8v a1 = *(const short8v*)&xbf[(size_t)rA * CIN + 32 + kg * 8];

    for (int kk8 = 0; kk8 < 8; kk8++) {
      int k = kg8 * 8 + kk8;
      if (k >= KTOT) break;  // uniform per block -> barrier-safe
      const unsigned short* wb = wbf + (size_t)k * 4096;
#pragma unroll
      for (int ct = 0; ct < 4; ct++) {
        int col = ct * 16 + lr;
        short8v b0 = *(const short8v*)&wb[col * 64 + kg * 8];
        short8v b1 = *(const short8v*)&wb[col * 64 + 32 + kg * 8];
        f32x4 c = {0.f, 0.f, 0.f, 0.f};
        c = __builtin_amdgcn_mfma_f32_16x16x32_bf16(a0, b0, c, 0, 0, 0);
        c = __builtin_amdgcn_mfma_f32_16x16x32_bf16(a1, b1, c, 0, 0, 0);
#pragma unroll
        for (int r = 0; r < 4; r++) {
          Sm[w * 16 + kg * 4 + r][ct * 16 + lr] = f2bf(c[r]);
        }
      }
      __syncthreads();  // stage complete

#pragma unroll
      for (int round = 0; round < 2; round++) {
        int rr = (tid >> 3) + round * 32;
        int ch = (tid & 7) * 8;
        int grow = n0 + rr;
        if (grow < Nx_) {
          uint4v v = *(const uint4v*)&Sm[rr][ch];
          __builtin_nontemporal_store(
              v, (uint4v*)&xw[((size_t)k * Nx_ + grow) * COUT + ch]);
        }
      }
      __syncthreads();  // store reads done before next k overwrites LDS
    }
  }
}

// ============ R: knn_rec (blocks first) | edge_sum (nt gathers) ============
__global__ __launch_bounds__(256) void phaseR_kernel(
    const float* __restrict__ vpart,
    const float4* __restrict__ pxp4, const float* __restrict__ pxb,
    const float* __restrict__ pos_y, const int* __restrict__ batch_y,
    const int* __restrict__ kptr, unsigned long long* __restrict__ part,
    int Ny_, int csize, int nb_knn, int nqb,
    const int* __restrict__ ei, const float* __restrict__ pseudo,
    const unsigned short* __restrict__ xw, float* __restrict__ acc,
    float* __restrict__ deg, int E_, int Nx_) {
  __shared__ char smem[5120];
  int bid = blockIdx.x;
  int tid = threadIdx.x;

  if (bid < nb_knn) {  // ---- knn_rec (verbatim math) ----
    int kk = *kptr;
    if (kk > 3) return;
    kk = kk < 1 ? 1 : kk;
    float4* lc = (float4*)smem;
    float* lb = (float*)(smem + 4096);
    const float FINF = __uint_as_float(0x7f800000u);

    int split = bid / nqb;
    int qy = (bid % nqb) * 256 + tid;
    int base0 = split * csize;

    int qc = qy < Ny_ ? qy : Ny_ - 1;
    float q0 = pos_y[qc * 3 + 0], q1 = pos_y[qc * 3 + 1], q2 = pos_y[qc * 3 + 2];
    float q3 = (float)batch_y[qc] * BM;
    float py2t = qnorm4(q0, q1, q2, q3);

    float t0v = FINF, t1v = FINF, t2v = FINF;
#pragma unroll
    for (int s = 0; s < NSPLIT; s++) {
      const float* vp = vpart + ((size_t)s * Ny_ + qc) * 3;
#pragma unroll
      for (int r = 0; r < 3; r++) {
        float v = vp[r];
        float n0 = fminf(v, t0v);
        float n1 = fminf(fmaxf(v, t0v), t1v);
        float n2 = fminf(fmaxf(v, t1v), t2v);
        t0v = n0; t1v = n1; t2v = n2;
      }
    }
    float thr = kk == 1 ? t0v : (kk == 2 ? t1v : t2v);

    unsigned long long k0 = ~0ull, k1 = ~0ull, k2 = ~0ull;

    for (int tb = 0; tb < csize; tb += 256) {
      int t = base0 + tb + tid;
      float4 cv;
      float cb;
      if (t < Nx_) {
        cv = pxp4[t];
        cb = pxb[t];
      } else {
        cv = make_float4(0.f, 0.f, 0.f, FINF);
        cb = 0.f;
      }
      __syncthreads();
      lc[tid] = cv;
      lb[tid] = cb;
      __syncthreads();

#pragma unroll 4
      for (int j = 0; j < 256; j++) {
        float d2 = dist2(q0, q1, q2, q3, py2t, lc[j], lb[j]);
        if (d2 <= thr) {
          unsigned long long key =
              (((unsigned long long)f32_orderable(d2)) << 32) |
              (unsigned)(base0 + tb + j);
          {
            bool lt = key < k0;
            unsigned long long nv = lt ? key : k0;
            unsigned long long xv = lt ? k0 : key;
            k0 = nv; key = xv;
          }
          {
            bool lt = key < k1;
            unsigned long long nv = lt ? key : k1;
            unsigned long long xv = lt ? k1 : key;
            k1 = nv; key = xv;
          }
          k2 = key < k2 ? key : k2;
        }
      }
    }

    if (qy < Ny_) {
      unsigned long long* pp = part + ((size_t)split * Ny_ + qy) * 3;
      pp[0] = k0;
      pp[1] = k1;
      pp[2] = k2;
    }
    return;
  }

  // ---- edge_sum (nt loads on xw) ----
  {
    int b = bid - nb_knn;
    int lane = tid & 63;
    int e = (int)(((size_t)b * 256 + tid) >> 6);
    if (e >= E_) return;
    int src = ei[e];
    int dst = ei[E_ + e];
    float bas[8];
    int kidx[8];
    edge_basis(pseudo, e, bas, kidx);

    float y = 0.f;
#pragma unroll
    for (int s = 0; s < 8; s++) {
      unsigned short v = __builtin_nontemporal_load(
          &xw[((size_t)kidx[s] * Nx_ + src) * COUT + lane]);
      y = fmaf(bas[s], bf2f(v), y);
    }
    atomicAdd(&acc[(size_t)dst * COUT + lane], y);
    if (lane == 0) atomicAdd(&deg[dst], 1.f);
  }
}

// ---------- node finish ----------
__global__ void node_finish_kernel(const float* __restrict__ x,
                                   const float* __restrict__ root,
                                   const float* __restrict__ bias,
                                   const float* __restrict__ acc,
                                   const float* __restrict__ deg,
                                   float* __restrict__ h, int Nx_) {
  int lane = threadIdx.x & 63;
  int n = (int)((blockIdx.x * blockDim.x + threadIdx.x) >> 6);
  if (n >= Nx_) return;
  float xs = x[(size_t)n * CIN + lane];
  float r = 0.f;
#pragma unroll 4
  for (int i = 0; i < CIN; i++) {
    float xv = __shfl(xs, i, 64);
    r = fmaf(xv, root[i * COUT + lane], r);
  }
  float d = deg[n];
  d = d > 1.f ? d : 1.f;
  float o = acc[(size_t)n * COUT + lane] / d + r + bias[lane];
  h[(size_t)n * COUT + lane] = (o > 0.f) ? o : expm1f(o);
}

// ---------- kNN merge + interp (fast path) OR generic k>3 (one kernel) ----------
__global__ void knn_merge_kernel(const unsigned long long* __restrict__ part,
                                 const float* __restrict__ h,
                                 const float4* __restrict__ pxp4,
                                 const float* __restrict__ pxb,
                                 const float* __restrict__ pos_y,
                                 const int* __restrict__ batch_y,
                                 const int* __restrict__ kptr,
                                 float* __restrict__ out, int Nx_, int Ny_) {
  int kk = *kptr;
  int lane = threadIdx.x & 63;
  int qy = (int)((blockIdx.x * blockDim.x + threadIdx.x) >> 6);
  if (qy >= Ny_) return;

  float num = 0.f, den = 0.f;

  if (kk <= 3) {
    kk = kk < 1 ? 1 : kk;
    unsigned long long key = ~0ull;
    if (lane < 3 * NSPLIT) {
      key = part[((size_t)(lane / 3) * Ny_ + qy) * 3 + (lane % 3)];
    }
    for (int i = 0; i < kk; i++) {
      unsigned long long m = wmin64(key);
      if (key == m) key = ~0ull;
      unsigned u = (unsigned)(m >> 32);
      int idx = (int)(m & 0xffffffffu);
      idx = (idx < 0 || idx >= Nx_) ? 0 : idx;
      float d2 = f32_unorderable(u);
      float w = 1.f / fmaxf(d2, 1e-16f);
      num = fmaf(w, h[(size_t)idx * COUT + lane], num);
      den += w;
    }
  } else {
    kk = kk > 8 ? 8 : kk;
    float q0 = pos_y[qy * 3 + 0], q1 = pos_y[qy * 3 + 1], q2 = pos_y[qy * 3 + 2];
    float q3 = (float)batch_y[qy] * BM;
    float py2t = qnorm4(q0, q1, q2, q3);

    unsigned long long best[8];
#pragma unroll
    for (int j = 0; j < 8; j++) best[j] = ~0ull;

    for (int t0 = 0; t0 < Nx_; t0 += 64) {
      int t = t0 + lane;
      unsigned long long key = ~0ull;
      if (t < Nx_) {
        float d2 = dist2(q0, q1, q2, q3, py2t, pxp4[t], pxb[t]);
        key = (((unsigned long long)f32_orderable(d2)) << 32) | (unsigned)t;
      }
      if (key < best[7]) {
#pragma unroll
        for (int j = 0; j < 8; j++) {
          unsigned long long mn = key < best[j] ? key : best[j];
          unsigned long long mx = key < best[j] ? best[j] : key;
          best[j] = mn;
          key = mx;
        }
      }
    }

    for (int j = 0; j < kk; j++) {
      unsigned long long m = wmin64(best[0]);
      if (best[0] == m) {
#pragma unroll
        for (int t = 0; t < 7; t++) best[t] = best[t + 1];
        best[7] = ~0ull;
      }
      unsigned u = (unsigned)(m >> 32);
      int idx = (int)(m & 0xffffffffu);
      idx = (idx < 0 || idx >= Nx_) ? 0 : idx;
      float d2 = f32_unorderable(u);
      float w = 1.f / fmaxf(d2, 1e-16f);
      num = fmaf(w, h[(size_t)idx * COUT + lane], num);
      den += w;
    }
  }

  out[(size_t)qy * COUT + lane] = num / den;
}

extern "C" void kernel_launch(void* const* d_in, const int* in_sizes, int n_in,
                              void* d_out, int out_size, void* d_ws, size_t ws_size,
                              hipStream_t stream) {
  const float* x = (const float*)d_in[0];
  const float* pos_x = (const float*)d_in[1];
  const float* pos_y = (const float*)d_in[2];
  const int* eidx = (const int*)d_in[3];
  const float* pseudo = (const float*)d_in[4];
  const int* batch_x = (const int*)d_in[5];
  const int* batch_y = (const int*)d_in[6];
  const float* W = (const float*)d_in[7];   // [125,64,64]
  const float* root = (const float*)d_in[8];
  const float* bias = (const float*)d_in[9];
  const int* kptr = (const int*)d_in[10];

  int Nx = in_sizes[0] / CIN;
  int Ny = in_sizes[2] / 3;
  int E = in_sizes[3] / 2;

  int csize = ((Nx + NSPLIT - 1) / NSPLIT + 255) & ~255;
  if (csize < 256) csize = 256;

  // ws layout: acc[Nx*64]f | deg[Nx]f | h[Nx*64]f | pxp4[Nx]float4 | pxb[Nx]f |
  //   xbf[Nx*64]u16 | wbf[125*4096]u16 | xw[125*Nx*64]u16 |
  //   vpart[NSPLIT*Ny*3]f | part[NSPLIT*Ny*3]u64
  float* acc = (float*)d_ws;
  float* deg = acc + (size_t)Nx * COUT;
  float* h = deg + Nx;
  float4* pxp4 = (float4*)(h + (size_t)Nx * COUT);
  float* pxb = (float*)(pxp4 + Nx);
  unsigned short* xbf = (unsigned short*)(pxb + Nx);
  unsigned short* wbf = xbf + (size_t)Nx * CIN;
  unsigned short* xw = wbf + (size_t)KTOT * CIN * COUT;
  float* vpart = (float*)(xw + (size_t)Nx * KTOT * COUT);
  uintptr_t paddr = (uintptr_t)(vpart + (size_t)NSPLIT * Ny * 3);
  paddr = (paddr + 7) & ~(uintptr_t)7;
  unsigned long long* part = (unsigned long long*)paddr;

  float* out = (float*)d_out;

  int n4 = Nx * CIN / 4;
  int nb_cvtx = (n4 + 255) / 256;
  int nb_pack = (Nx + 255) / 256;
  int nz4 = (Nx * COUT + Nx) / 4;  // acc+deg floats / 4 (Nx*65 % 4 == 0)
  int nb_zero = (nz4 + 255) / 256;
  int nqb = (Ny + 255) / 256;
  int nb_knn = nqb * NSPLIT;
  int nxb = (Nx + 63) / 64;
  int nkg8 = (KTOT + 7) / 8;       // 16
  int nb_xw = nxb * nkg8;
  int nb_edge = (int)(((size_t)E * WAVE + 255) / 256);

  // P: zero | cvtx | cvtw | pack
  pre_kernel<<<nb_zero + nb_cvtx + KTOT + nb_pack, 256, 0, stream>>>(
      x, xbf, n4, W, wbf, pos_x, batch_x, pxp4, pxb, Nx, acc, nz4, nb_zero,
      nb_cvtx);

  // Q: knn_val first | xw_mfma 8-k batched (nt stores)
  phaseQ_kernel<<<nb_knn + nb_xw, 256, 0, stream>>>(
      pxp4, pxb, pos_y, batch_y, kptr, vpart, Ny, csize, nb_knn, nqb,
      xbf, wbf, xw, Nx, nxb);

  // R: knn_rec first | edge_sum (nt gathers)
  phaseR_kernel<<<nb_knn + nb_edge, 256, 0, stream>>>(
      vpart, pxp4, pxb, pos_y, batch_y, kptr, part, Ny, csize, nb_knn, nqb,
      eidx, pseudo, xw, acc, deg, E, Nx);

  {
    int blocks = (Nx * WAVE + 255) / 256;
    node_finish_kernel<<<blocks, 256, 0, stream>>>(x, root, bias, acc, deg, h, Nx);
  }
  {
    int blocks = (Ny * WAVE + 255) / 256;
    knn_merge_kernel<<<blocks, 256, 0, stream>>>(part, h, pxp4, pxb, pos_y,
                                                 batch_y, kptr, out, Nx, Ny);
  }
}